// Round 12
// baseline (285.510 us; speedup 1.0000x reference)
//
#include <hip/hip_runtime.h>
#include <math.h>

#define NSMP 48
#define FSTR 88    // feat row stride in f16 (72 data + 16 slack; 176B: 16B-aligned, period-8 banks)
#define HSTR 72    // hid row stride in f16 (64 + 8 pad; 144B, 16B-aligned)
#define WAVES 3
#define LUTN 256   // gelu LUT entries over [-8,8], step 1/16

typedef _Float16 f16;
typedef _Float16 half8 __attribute__((ext_vector_type(8)));
typedef _Float16 half4 __attribute__((ext_vector_type(4)));
typedef _Float16 h2    __attribute__((ext_vector_type(2)));
typedef float    f32x4 __attribute__((ext_vector_type(4)));

__device__ __forceinline__ float sigmoid_f(float x){
    return __builtin_amdgcn_rcpf(1.0f + __expf(-x));
}
// gelu via LDS LUT, slope-intercept form: val = x * (c0[i] + u*c1[i])
__device__ __forceinline__ float gelu_lut(float x, const float2* __restrict__ lut){
    float u = __builtin_fmaf(x, 16.0f, 128.0f);
    u = fminf(fmaxf(u, 0.0f), 255.0f);
    const float2 e = lut[(int)u];
    return x * __builtin_fmaf(u, e.y, e.x);
}
// wave-synchronous LDS fence (per-wave LDS regions)
#define LDS_FENCE() asm volatile("s_waitcnt lgkmcnt(0)" ::: "memory")

template<bool TR>
__global__ __launch_bounds__(WAVES*64, 4)
void render_kernel(const float* __restrict__ rays_o,
                   const float* __restrict__ rays_d,
                   const f16*   __restrict__ mats16,  // TR: [ib][pix][32] f16
                   const f16*   __restrict__ vecs16,  // TR: [ib][r][32] f16
                   const float* __restrict__ matsf,   // !TR: original f32 layout
                   const float* __restrict__ vecsf,
                   const f16*   __restrict__ wT,      // [64][96] f16, 0-pad k>=72
                   const float* __restrict__ g_bmat,
                   const f16*   __restrict__ w1T,     // [64][64] f16
                   const float* __restrict__ g_b1,
                   const float* __restrict__ g_w1,    // f32 w1 (PE rows 64..90)
                   const float* __restrict__ g_w2,
                   const float* __restrict__ g_b2,
                   float* __restrict__ out, int B, int R)
{
    __shared__ f16 s_buf[WAVES][NSMP*FSTR];   // 25344 B (feat, then hid overlays)
    __shared__ float2 s_lut[LUTN];            // 2048 B  -> total 27392 B: 5 blocks/CU

    const int tid  = threadIdx.x;

    // build gelu LUT (block-shared), BEFORE any wave can exit
    for (int i = tid; i < LUTN; i += WAVES*64){
        const float x0 = -8.0f + (float)i * 0.0625f;
        const float p0 = 0.5f*(1.0f + erff( x0          *0.70710678118654752f));
        const float p1 = 0.5f*(1.0f + erff((x0+0.0625f) *0.70710678118654752f));
        const float slope = p1 - p0;
        float2 e; e.y = slope; e.x = p0 - (float)i*slope;
        s_lut[i] = e;
    }
    __syncthreads();
    const float2* lut = s_lut;

    const int wv   = tid >> 6;
    const int lane = tid & 63;
    const int NR   = B*R;
    const int ray  = blockIdx.x*WAVES + wv;
    if (ray >= NR) return;                    // wave-uniform exit (after barrier)
    const int b = ray / R;

    f16* gF = s_buf[wv];
    f16* gH = s_buf[wv];                      // overlay (48*72 fits in 48*88 region)

    const float ox=rays_o[ray*3+0], oy=rays_o[ray*3+1], oz=rays_o[ray*3+2];
    const float dx=rays_d[ray*3+0], dy=rays_d[ray*3+1], dz=rays_d[ray*3+2];

    // ================= Phase 1: gather (lane = sample) =================
    const int  s      = lane;
    const bool active = (s < NSMP);
    const int  sc     = active ? s : (NSMP-1);
    const float mid   = ((float)s  + 0.5f) * 0.03125f;
    const float midc  = ((float)sc + 0.5f) * 0.03125f;

    const float x0c = 1.25f*(ox + dx*midc);
    const float x1c = 1.25f*(oy + dy*midc);
    const float x2c = 1.25f*(oz + dz*midc);

    float sigma = 0.0f;

    #pragma unroll 1
    for (int i=0;i<3;i++){
        // MAT_MODE = {{0,1},{2,0},{1,2}}, VEC_MODE = {2,1,0}
        const float cx = (i==0)? x0c : (i==1)? x2c : x1c;
        const float cy = (i==0)? x1c : (i==1)? x0c : x2c;
        const float cv = (i==0)? x2c : (i==1)? x1c : x0c;

        const float px = (cx+1.0f)*23.5f;
        const float py = (cy+1.0f)*23.5f;
        const float fx0 = floorf(px), fy0 = floorf(py);
        const float wx = px-fx0, wy = py-fy0;
        const int ix0 = (int)fx0, iy0 = (int)fy0;

        int   toff[4];
        float tw[4];
        #pragma unroll
        for (int t=0;t<4;t++){
            const int xx = ix0 + (t&1);
            const int yy = iy0 + (t>>1);
            const bool inb = (xx>=0)&&(xx<48)&&(yy>=0)&&(yy<48);
            const int xcl = min(max(xx,0),47);
            const int ycl = min(max(yy,0),47);
            toff[t] = ycl*48+xcl;
            const float wxx = (t&1)? wx : 1.0f-wx;
            const float wyy = (t>>1)? wy : 1.0f-wy;
            tw[t] = inb ? wxx*wyy : 0.0f;
        }

        const float pv = (cv+1.0f)*23.5f;
        const float fp0 = floorf(pv);
        const float wvv = pv-fp0;
        const int ip0 = (int)fp0;
        int voff[2]; float vw[2];
        #pragma unroll
        for (int t=0;t<2;t++){
            const int pp = ip0+t;
            const bool inb = (pp>=0)&&(pp<48);
            voff[t] = min(max(pp,0),47);
            vw[t] = inb ? ((t)? wvv : 1.0f-wvv) : 0.0f;
        }

        if (TR){
            const f16* pb = mats16 + ((size_t)(i*B+b))*(2304u*32u);
            const f16* vb = vecs16 + ((size_t)(i*B+b))*(48u*32u);
            const half8* t0 = (const half8*)(pb + toff[0]*32);
            const half8* t1 = (const half8*)(pb + toff[1]*32);
            const half8* t2 = (const half8*)(pb + toff[2]*32);
            const half8* t3 = (const half8*)(pb + toff[3]*32);
            const half8* v0 = (const half8*)(vb + voff[0]*32);
            const half8* v1 = (const half8*)(vb + voff[1]*32);

            const h2 tw0h = {(f16)tw[0],(f16)tw[0]};
            const h2 tw1h = {(f16)tw[1],(f16)tw[1]};
            const h2 tw2h = {(f16)tw[2],(f16)tw[2]};
            const h2 tw3h = {(f16)tw[3],(f16)tw[3]};
            const h2 vw0h = {(f16)vw[0],(f16)vw[0]};
            const h2 vw1h = {(f16)vw[1],(f16)vw[1]};

            // 8 channels per iter, packed-f16 blend
            #pragma unroll 2
            for (int c4=0;c4<4;c4++){
                const half8 a0=t0[c4], a1=t1[c4], a2=t2[c4], a3=t3[c4];
                const half8 q0=v0[c4], q1=v1[c4];
                float g[8];
                #pragma unroll
                for (int j=0;j<4;j++){
                    const h2 a0j = {a0[2*j], a0[2*j+1]};
                    const h2 a1j = {a1[2*j], a1[2*j+1]};
                    const h2 a2j = {a2[2*j], a2[2*j+1]};
                    const h2 a3j = {a3[2*j], a3[2*j+1]};
                    const h2 q0j = {q0[2*j], q0[2*j+1]};
                    const h2 q1j = {q1[2*j], q1[2*j+1]};
                    h2 pf = a0j*tw0h; pf += a1j*tw1h; pf += a2j*tw2h; pf += a3j*tw3h;
                    h2 vf = q0j*vw0h; vf += q1j*vw1h;
                    const h2 fj = pf*vf;
                    if (c4==0){
                        sigma += (float)fj[0] + (float)fj[1];
                    } else {
                        g[2*j]   = gelu_lut((float)fj[0], lut);
                        g[2*j+1] = gelu_lut((float)fj[1], lut);
                    }
                }
                if (c4>0 && active){
                    half8 hv = {(f16)g[0],(f16)g[1],(f16)g[2],(f16)g[3],
                                (f16)g[4],(f16)g[5],(f16)g[6],(f16)g[7]};
                    *(half8*)(gF + s*FSTR + i*24 + c4*8 - 8) = hv;
                }
            }
        } else {
            const float* pb = matsf + ((size_t)(i*B+b))*(32u*2304u);
            const float* vb = vecsf + ((size_t)(i*B+b))*(32u*48u);
            #pragma unroll 2
            for (int c=0;c<32;c++){
                const float* fc = pb + c*2304;
                const float pf = tw[0]*fc[toff[0]] + tw[1]*fc[toff[1]]
                               + tw[2]*fc[toff[2]] + tw[3]*fc[toff[3]];
                const float* vc = vb + c*48;
                const float vf = vw[0]*vc[voff[0]] + vw[1]*vc[voff[1]];
                const float r = pf*vf;
                if (c < 8) sigma += r;
                else if (active) gF[s*FSTR + i*24 + c - 8] = (f16)gelu_lut(r, lut);
            }
        }
    }
    // no K-pad zeroing needed: the 3rd K-step zeroes its B-frag in registers

    const int q  = lane >> 4;   // quad
    const int cl = lane & 15;   // col index within tile

    // ======== Phase 2: layer-1 GEMM  hid^T(64x48) = wT(64x96) @ feat^T(96x48) ========
    f32x4 acc[4][3];
    #pragma unroll
    for (int mt=0;mt<4;mt++){
        const float4 bmv = *(const float4*)(g_bmat + mt*16 + q*4);
        #pragma unroll
        for (int nt=0;nt<3;nt++){
            acc[mt][nt][0]=bmv.x; acc[mt][nt][1]=bmv.y; acc[mt][nt][2]=bmv.z; acc[mt][nt][3]=bmv.w;
        }
    }

    LDS_FENCE();   // feat writes visible to whole wave

    #pragma unroll 1
    for (int ks=0; ks<2; ks++){
        half8 bf[3];
        #pragma unroll
        for (int nt=0;nt<3;nt++)
            bf[nt] = *(const half8*)(gF + (nt*16+cl)*FSTR + ks*32 + q*8);
        #pragma unroll
        for (int mt=0;mt<4;mt++){
            const half8 af = *(const half8*)(wT + (mt*16+cl)*96 + ks*32 + q*8);
            #pragma unroll
            for (int nt=0;nt<3;nt++)
                acc[mt][nt] = __builtin_amdgcn_mfma_f32_16x16x32_f16(af, bf[nt], acc[mt][nt], 0,0,0);
        }
    }
    {   // ks=2: k = 64 + q*8. Only q==0 holds real B data (k=64..71); wT rows k>=72 are
        // zero-padded so q>0 lanes' A-frag is 0 and their B value is irrelevant — but we
        // zero it anyway to avoid reading uninitialized LDS (NaN poison).
        half8 bf[3] = {{0,0,0,0,0,0,0,0},{0,0,0,0,0,0,0,0},{0,0,0,0,0,0,0,0}};
        if (q == 0){
            #pragma unroll
            for (int nt=0;nt<3;nt++)
                bf[nt] = *(const half8*)(gF + (nt*16+cl)*FSTR + 64);
        }
        #pragma unroll
        for (int mt=0;mt<4;mt++){
            const half8 af = *(const half8*)(wT + (mt*16+cl)*96 + 64 + q*8);
            #pragma unroll
            for (int nt=0;nt<3;nt++)
                acc[mt][nt] = __builtin_amdgcn_mfma_f32_16x16x32_f16(af, bf[nt], acc[mt][nt], 0,0,0);
        }
    }

    // gelu + pack + store hid^T into the SAME LDS region
    LDS_FENCE();   // all feat reads drained before overwrite
    #pragma unroll
    for (int mt=0;mt<4;mt++){
        #pragma unroll
        for (int nt=0;nt<3;nt++){
            half4 hv = {(f16)gelu_lut(acc[mt][nt][0], lut), (f16)gelu_lut(acc[mt][nt][1], lut),
                        (f16)gelu_lut(acc[mt][nt][2], lut), (f16)gelu_lut(acc[mt][nt][3], lut)};
            *(half4*)(gH + (nt*16+cl)*HSTR + mt*16 + q*4) = hv;
        }
    }

    // ================= Phase 3: PE fold (lane = hidden j) =================
    float pe = g_b1[lane];
    {
        const float inv_n = rsqrtf(dx*dx+dy*dy+dz*dz);
        const float vd0=dx*inv_n, vd1=dy*inv_n, vd2=dz*inv_n;
        pe += vd0*g_w1[64*64+lane] + vd1*g_w1[65*64+lane] + vd2*g_w1[66*64+lane];
        #pragma unroll 1
        for (int fq=0; fq<4; fq++){
            const float fs = (float)(1<<fq);
            float s0,c0,s1,c1,s2,c2;
            __sincosf(vd0*fs, &s0, &c0);
            __sincosf(vd1*fs, &s1, &c1);
            __sincosf(vd2*fs, &s2, &c2);
            pe += s0*g_w1[(67+fq*3+0)*64+lane];
            pe += s1*g_w1[(67+fq*3+1)*64+lane];
            pe += s2*g_w1[(67+fq*3+2)*64+lane];
            pe += c0*g_w1[(79+fq*3+0)*64+lane];
            pe += c1*g_w1[(79+fq*3+1)*64+lane];
            pe += c2*g_w1[(79+fq*3+2)*64+lane];
        }
    }

    // ======== Phase 4: layer-2 GEMM  h2^T(64x48) = w1T(64x64) @ hid^T(64x48) ========
    f32x4 acc2[4][3];
    #pragma unroll
    for (int mt=0;mt<4;mt++){
        const float p0 = __shfl(pe, mt*16+q*4+0, 64);
        const float p1 = __shfl(pe, mt*16+q*4+1, 64);
        const float p2 = __shfl(pe, mt*16+q*4+2, 64);
        const float p3 = __shfl(pe, mt*16+q*4+3, 64);
        #pragma unroll
        for (int nt=0;nt<3;nt++){
            acc2[mt][nt][0]=p0; acc2[mt][nt][1]=p1; acc2[mt][nt][2]=p2; acc2[mt][nt][3]=p3;
        }
    }

    LDS_FENCE();   // hid writes visible

    #pragma unroll 1
    for (int ks=0; ks<2; ks++){
        half8 bf[3];
        #pragma unroll
        for (int nt=0;nt<3;nt++)
            bf[nt] = *(const half8*)(gH + (nt*16+cl)*HSTR + ks*32 + q*8);
        #pragma unroll
        for (int mt=0;mt<4;mt++){
            const half8 af = *(const half8*)(w1T + (mt*16+cl)*64 + ks*32 + q*8);
            #pragma unroll
            for (int nt=0;nt<3;nt++)
                acc2[mt][nt] = __builtin_amdgcn_mfma_f32_16x16x32_f16(af, bf[nt], acc2[mt][nt], 0,0,0);
        }
    }

    // ======== Phase 5: layer 3 + sigmoid, straight from C-registers ========
    const float b20=g_b2[0], b21=g_b2[1], b22=g_b2[2];
    float rgb0=0.0f, rgb1=0.0f, rgb2=0.0f;
    #pragma unroll
    for (int nt=0;nt<3;nt++){
        float r0=0.0f, r1=0.0f, r2=0.0f;
        #pragma unroll
        for (int mt=0;mt<4;mt++){
            const float4* wp = (const float4*)(g_w2 + (size_t)(mt*16+q*4)*3);
            const float4 wa = wp[0], wb = wp[1], wc = wp[2];
            const float g0 = gelu_lut(acc2[mt][nt][0], lut);
            const float g1 = gelu_lut(acc2[mt][nt][1], lut);
            const float g2 = gelu_lut(acc2[mt][nt][2], lut);
            const float g3 = gelu_lut(acc2[mt][nt][3], lut);
            r0 += g0*wa.x + g1*wa.w + g2*wb.z + g3*wc.y;
            r1 += g0*wa.y + g1*wb.x + g2*wb.w + g3*wc.z;
            r2 += g0*wa.z + g1*wb.y + g2*wc.x + g3*wc.w;
        }
        r0 += __shfl_xor(r0, 16, 64);  r0 += __shfl_xor(r0, 32, 64);
        r1 += __shfl_xor(r1, 16, 64);  r1 += __shfl_xor(r1, 32, 64);
        r2 += __shfl_xor(r2, 16, 64);  r2 += __shfl_xor(r2, 32, 64);
        if (q == nt){
            rgb0 = sigmoid_f(r0+b20);
            rgb1 = sigmoid_f(r1+b21);
            rgb2 = sigmoid_f(r2+b22);
        }
    }

    // ======== Phase 6: volume integration (lane = sample) ========
    const float sg    = fmaxf(sigma, 0.0f);
    const float alpha = active ? (1.0f - __expf(-sg*0.03125f)) : 0.0f;
    float v = active ? (1.0f - alpha + 1e-10f) : 1.0f;
    #pragma unroll
    for (int off=1; off<64; off<<=1){
        const float up = __shfl_up(v, off, 64);
        if (lane >= off) v *= up;
    }
    float T = __shfl_up(v, 1, 64);
    if (lane==0) T = 1.0f;
    const float w = alpha*T;

    if (active) out[(size_t)NR*4 + (size_t)ray*NSMP + s] = w;

    float A0=w*rgb0, A1=w*rgb1, A2=w*rgb2, AD=w*mid;
    #pragma unroll
    for (int off=32; off>0; off>>=1){
        A0 += __shfl_down(A0, off, 64);
        A1 += __shfl_down(A1, off, 64);
        A2 += __shfl_down(A2, off, 64);
        AD += __shfl_down(AD, off, 64);
    }
    if (lane==0){
        out[(size_t)ray*3+0]=A0;
        out[(size_t)ray*3+1]=A1;
        out[(size_t)ray*3+2]=A2;
        out[(size_t)NR*3 + (size_t)ray]=AD;
    }
}

// One fused prep kernel:
//  blocks [0, tileN)          : LDS-tiled mats transpose f32 [ib][32][2304] -> f16 [ib][2304][32]
//  blocks [tileN, tileN+prepN): vec transpose + weight prep (linear index)
__global__ __launch_bounds__(256)
void fused_prep(const float* __restrict__ mats, const float* __restrict__ vecs,
                const float* __restrict__ w_mat, const float* __restrict__ w1,
                f16* __restrict__ tm, f16* __restrict__ tv,
                f16* __restrict__ wT, f16* __restrict__ w1T,
                int tileN, int vecsz){
    __shared__ float tl[32][33];
    const int bid = blockIdx.x;
    if (bid < tileN){
        const int ib   = bid / 72;
        const int pix0 = (bid % 72) * 32;
        const int tx = threadIdx.x & 31;
        const int ty = threadIdx.x >> 5;      // 0..7
        const float* src = mats + (size_t)ib*32*2304;
        #pragma unroll
        for (int t=0;t<4;t++){
            const int c = ty + t*8;
            tl[c][tx] = src[(size_t)c*2304 + pix0 + tx];
        }
        __syncthreads();
        f16* dst = tm + (size_t)ib*2304*32;
        #pragma unroll
        for (int t=0;t<4;t++){
            const int p = ty + t*8;
            dst[(size_t)(pix0+p)*32 + tx] = (f16)tl[tx][p];
        }
    } else {
        const int idx = (bid - tileN)*256 + threadIdx.x;
        if (idx < vecsz){
            const int r  = idx % 48;
            const int c  = (idx / 48) & 31;
            const int ib = idx / (48*32);
            tv[((size_t)ib*48+r)*32 + c] = (f16)vecs[idx];
        } else if (idx < vecsz + 64*96){
            const int i1 = idx - vecsz;
            const int n = i1 / 96, k = i1 % 96;
            wT[i1] = (k < 72) ? (f16)w_mat[k*64+n] : (f16)0.0f;
        } else if (idx < vecsz + 64*96 + 64*64){
            const int i2 = idx - vecsz - 64*96;
            const int n = i2 / 64, k = i2 % 64;
            w1T[i2] = (f16)w1[k*64+n];
        }
    }
}

extern "C" void kernel_launch(void* const* d_in, const int* in_sizes, int n_in,
                              void* d_out, int out_size, void* d_ws, size_t ws_size,
                              hipStream_t stream) {
    const float* rays_o  = (const float*)d_in[0];
    const float* rays_d  = (const float*)d_in[1];
    const float* matrixs = (const float*)d_in[2];
    const float* vectors = (const float*)d_in[3];
    const float* w_mat   = (const float*)d_in[4];
    const float* b_mat   = (const float*)d_in[5];
    const float* w1      = (const float*)d_in[6];
    const float* b1      = (const float*)d_in[7];
    const float* w2      = (const float*)d_in[8];
    const float* b2      = (const float*)d_in[9];
    float* out = (float*)d_out;

    const int B = in_sizes[2] / (3*32*48*48);
    const int R = (in_sizes[0]/3) / B;
    const int NR = B*R;

    const int matsz = 3*B*32*2304;
    const int vecsz = 3*B*32*48;
    const size_t need_full = ((size_t)matsz + (size_t)vecsz)*sizeof(f16)
                           + (size_t)(64*96+64*64)*sizeof(f16);
    const size_t need_w    = (size_t)(64*96+64*64)*sizeof(f16);

    const int nblk = (NR + WAVES-1)/WAVES;
    const int nthr = WAVES*64;

    if (ws_size >= need_full){
        f16* tm  = (f16*)d_ws;
        f16* tv  = tm + matsz;
        f16* wT  = tv + vecsz;
        f16* w1T = wT + 64*96;
        const int tileN = 72*3*B;
        const int smalln = vecsz + 64*96 + 64*64;
        const int prepN  = (smalln + 255)/256;
        fused_prep<<<tileN + prepN, 256, 0, stream>>>(matrixs, vectors, w_mat, w1,
                                                      tm, tv, wT, w1T, tileN, vecsz);
        render_kernel<true><<<nblk, nthr, 0, stream>>>(rays_o, rays_d, tm, tv,
            nullptr, nullptr, wT, b_mat, w1T, b1, w1, w2, b2, out, B, R);
    } else if (ws_size >= need_w){
        f16* wT  = (f16*)d_ws;
        f16* w1T = wT + 64*96;
        const int smalln = 64*96 + 64*64;
        fused_prep<<<(smalln+255)/256, 256, 0, stream>>>(nullptr, nullptr, w_mat, w1,
                                                         nullptr, nullptr, wT, w1T, 0, 0);
        render_kernel<false><<<nblk, nthr, 0, stream>>>(rays_o, rays_d,
            nullptr, nullptr, matrixs, vectors, wT, b_mat, w1T, b1, w1, w2, b2, out, B, R);
    }
}

// Round 13
// 283.402 us; speedup vs baseline: 1.0074x; 1.0074x over previous
//
#include <hip/hip_runtime.h>
#include <math.h>

#define NSMP 48
#define FSTR 72    // feat row stride in f16 (72 data, no pad; 144B rows, 16B-aligned, 2-way banks = free)
#define HSTR 72    // hid row stride in f16 (64 + 8 pad; 144B, 16B-aligned)
#define WAVES 4
#define LUTN 256   // gelu LUT entries over [-8,8], step 1/16

typedef _Float16 f16;
typedef _Float16 half8 __attribute__((ext_vector_type(8)));
typedef _Float16 half4 __attribute__((ext_vector_type(4)));
typedef _Float16 h2    __attribute__((ext_vector_type(2)));
typedef float    f32x4 __attribute__((ext_vector_type(4)));

__device__ __forceinline__ float sigmoid_f(float x){
    return __builtin_amdgcn_rcpf(1.0f + __expf(-x));
}
// gelu via LDS LUT, slope-intercept form: val = x * (c0[i] + u*c1[i])
__device__ __forceinline__ float gelu_lut(float x, const float2* __restrict__ lut){
    float u = __builtin_fmaf(x, 16.0f, 128.0f);
    u = fminf(fmaxf(u, 0.0f), 255.0f);
    const float2 e = lut[(int)u];
    return x * __builtin_fmaf(u, e.y, e.x);
}
// wave-synchronous LDS fence (per-wave LDS regions)
#define LDS_FENCE() asm volatile("s_waitcnt lgkmcnt(0)" ::: "memory")

template<bool TR>
__global__ __launch_bounds__(WAVES*64, 4)
void render_kernel(const float* __restrict__ rays_o,
                   const float* __restrict__ rays_d,
                   const f16*   __restrict__ mats16,  // TR: [ib][pix][32] f16
                   const f16*   __restrict__ vecs16,  // TR: [ib][r][32] f16
                   const float* __restrict__ matsf,   // !TR: original f32 layout
                   const float* __restrict__ vecsf,
                   const f16*   __restrict__ wT,      // [64][96] f16, 0-pad k>=72
                   const float* __restrict__ g_bmat,
                   const f16*   __restrict__ w1T,     // [64][64] f16
                   const float* __restrict__ g_b1,
                   const float* __restrict__ g_w1,    // f32 w1 (PE rows 64..90)
                   const float* __restrict__ g_w2,
                   const float* __restrict__ g_b2,
                   float* __restrict__ out, int B, int R)
{
    __shared__ f16 s_buf[WAVES][NSMP*FSTR];   // 27648 B (feat, then hid overlays)
    __shared__ float2 s_lut[LUTN];            // 2048 B  -> 29696 B total; 4 waves/block

    const int tid  = threadIdx.x;

    // build gelu LUT (block-shared), BEFORE any wave can exit
    for (int i = tid; i < LUTN; i += WAVES*64){
        const float x0 = -8.0f + (float)i * 0.0625f;
        const float p0 = 0.5f*(1.0f + erff( x0          *0.70710678118654752f));
        const float p1 = 0.5f*(1.0f + erff((x0+0.0625f) *0.70710678118654752f));
        const float slope = p1 - p0;
        float2 e; e.y = slope; e.x = p0 - (float)i*slope;
        s_lut[i] = e;
    }
    __syncthreads();
    const float2* lut = s_lut;

    const int wv   = tid >> 6;
    const int lane = tid & 63;
    const int NR   = B*R;
    const int ray  = blockIdx.x*WAVES + wv;
    if (ray >= NR) return;                    // wave-uniform exit (after barrier)
    const int b = ray / R;

    f16* gF = s_buf[wv];
    f16* gH = s_buf[wv];                      // overlay (48*72 hid == 48*72 feat region)

    const float ox=rays_o[ray*3+0], oy=rays_o[ray*3+1], oz=rays_o[ray*3+2];
    const float dx=rays_d[ray*3+0], dy=rays_d[ray*3+1], dz=rays_d[ray*3+2];

    // ================= Phase 1: gather (lane = sample) =================
    const int  s      = lane;
    const bool active = (s < NSMP);
    const int  sc     = active ? s : (NSMP-1);
    const float mid   = ((float)s  + 0.5f) * 0.03125f;
    const float midc  = ((float)sc + 0.5f) * 0.03125f;

    const float x0c = 1.25f*(ox + dx*midc);
    const float x1c = 1.25f*(oy + dy*midc);
    const float x2c = 1.25f*(oz + dz*midc);

    float sigma = 0.0f;

    #pragma unroll 1
    for (int i=0;i<3;i++){
        // MAT_MODE = {{0,1},{2,0},{1,2}}, VEC_MODE = {2,1,0}
        const float cx = (i==0)? x0c : (i==1)? x2c : x1c;
        const float cy = (i==0)? x1c : (i==1)? x0c : x2c;
        const float cv = (i==0)? x2c : (i==1)? x1c : x0c;

        const float px = (cx+1.0f)*23.5f;
        const float py = (cy+1.0f)*23.5f;
        const float fx0 = floorf(px), fy0 = floorf(py);
        const float wx = px-fx0, wy = py-fy0;
        const int ix0 = (int)fx0, iy0 = (int)fy0;

        int   toff[4];
        float tw[4];
        #pragma unroll
        for (int t=0;t<4;t++){
            const int xx = ix0 + (t&1);
            const int yy = iy0 + (t>>1);
            const bool inb = (xx>=0)&&(xx<48)&&(yy>=0)&&(yy<48);
            const int xcl = min(max(xx,0),47);
            const int ycl = min(max(yy,0),47);
            toff[t] = ycl*48+xcl;
            const float wxx = (t&1)? wx : 1.0f-wx;
            const float wyy = (t>>1)? wy : 1.0f-wy;
            tw[t] = inb ? wxx*wyy : 0.0f;
        }

        const float pv = (cv+1.0f)*23.5f;
        const float fp0 = floorf(pv);
        const float wvv = pv-fp0;
        const int ip0 = (int)fp0;
        int voff[2]; float vw[2];
        #pragma unroll
        for (int t=0;t<2;t++){
            const int pp = ip0+t;
            const bool inb = (pp>=0)&&(pp<48);
            voff[t] = min(max(pp,0),47);
            vw[t] = inb ? ((t)? wvv : 1.0f-wvv) : 0.0f;
        }

        if (TR){
            const f16* pb = mats16 + ((size_t)(i*B+b))*(2304u*32u);
            const f16* vb = vecs16 + ((size_t)(i*B+b))*(48u*32u);
            const half8* t0 = (const half8*)(pb + toff[0]*32);
            const half8* t1 = (const half8*)(pb + toff[1]*32);
            const half8* t2 = (const half8*)(pb + toff[2]*32);
            const half8* t3 = (const half8*)(pb + toff[3]*32);
            const half8* v0 = (const half8*)(vb + voff[0]*32);
            const half8* v1 = (const half8*)(vb + voff[1]*32);

            const h2 tw0h = {(f16)tw[0],(f16)tw[0]};
            const h2 tw1h = {(f16)tw[1],(f16)tw[1]};
            const h2 tw2h = {(f16)tw[2],(f16)tw[2]};
            const h2 tw3h = {(f16)tw[3],(f16)tw[3]};
            const h2 vw0h = {(f16)vw[0],(f16)vw[0]};
            const h2 vw1h = {(f16)vw[1],(f16)vw[1]};

            // 8 channels per iter, packed-f16 blend
            #pragma unroll 2
            for (int c4=0;c4<4;c4++){
                const half8 a0=t0[c4], a1=t1[c4], a2=t2[c4], a3=t3[c4];
                const half8 q0=v0[c4], q1=v1[c4];
                float g[8];
                #pragma unroll
                for (int j=0;j<4;j++){
                    const h2 a0j = {a0[2*j], a0[2*j+1]};
                    const h2 a1j = {a1[2*j], a1[2*j+1]};
                    const h2 a2j = {a2[2*j], a2[2*j+1]};
                    const h2 a3j = {a3[2*j], a3[2*j+1]};
                    const h2 q0j = {q0[2*j], q0[2*j+1]};
                    const h2 q1j = {q1[2*j], q1[2*j+1]};
                    h2 pf = a0j*tw0h; pf += a1j*tw1h; pf += a2j*tw2h; pf += a3j*tw3h;
                    h2 vf = q0j*vw0h; vf += q1j*vw1h;
                    const h2 fj = pf*vf;
                    if (c4==0){
                        sigma += (float)fj[0] + (float)fj[1];
                    } else {
                        g[2*j]   = gelu_lut((float)fj[0], lut);
                        g[2*j+1] = gelu_lut((float)fj[1], lut);
                    }
                }
                if (c4>0 && active){
                    half8 hv = {(f16)g[0],(f16)g[1],(f16)g[2],(f16)g[3],
                                (f16)g[4],(f16)g[5],(f16)g[6],(f16)g[7]};
                    *(half8*)(gF + s*FSTR + i*24 + c4*8 - 8) = hv;
                }
            }
        } else {
            const float* pb = matsf + ((size_t)(i*B+b))*(32u*2304u);
            const float* vb = vecsf + ((size_t)(i*B+b))*(32u*48u);
            #pragma unroll 2
            for (int c=0;c<32;c++){
                const float* fc = pb + c*2304;
                const float pf = tw[0]*fc[toff[0]] + tw[1]*fc[toff[1]]
                               + tw[2]*fc[toff[2]] + tw[3]*fc[toff[3]];
                const float* vc = vb + c*48;
                const float vf = vw[0]*vc[voff[0]] + vw[1]*vc[voff[1]];
                const float r = pf*vf;
                if (c < 8) sigma += r;
                else if (active) gF[s*FSTR + i*24 + c - 8] = (f16)gelu_lut(r, lut);
            }
        }
    }
    // no K-pad region: 3rd K-step zeroes its B-frag in registers

    const int q  = lane >> 4;   // quad
    const int cl = lane & 15;   // col index within tile

    // ======== Phase 2: layer-1 GEMM  hid^T(64x48) = wT(64x96) @ feat^T(96x48) ========
    f32x4 acc[4][3];
    #pragma unroll
    for (int mt=0;mt<4;mt++){
        const float4 bmv = *(const float4*)(g_bmat + mt*16 + q*4);
        #pragma unroll
        for (int nt=0;nt<3;nt++){
            acc[mt][nt][0]=bmv.x; acc[mt][nt][1]=bmv.y; acc[mt][nt][2]=bmv.z; acc[mt][nt][3]=bmv.w;
        }
    }

    LDS_FENCE();   // feat writes visible to whole wave

    #pragma unroll 1
    for (int ks=0; ks<2; ks++){
        half8 bf[3];
        #pragma unroll
        for (int nt=0;nt<3;nt++)
            bf[nt] = *(const half8*)(gF + (nt*16+cl)*FSTR + ks*32 + q*8);
        #pragma unroll
        for (int mt=0;mt<4;mt++){
            const half8 af = *(const half8*)(wT + (mt*16+cl)*96 + ks*32 + q*8);
            #pragma unroll
            for (int nt=0;nt<3;nt++)
                acc[mt][nt] = __builtin_amdgcn_mfma_f32_16x16x32_f16(af, bf[nt], acc[mt][nt], 0,0,0);
        }
    }
    {   // ks=2: k = 64 + q*8. Only q==0 holds real B data (k=64..71); wT rows k>=72 are
        // zero-padded so q>0 lanes contribute 0 regardless; zero B to avoid reading OOB LDS.
        half8 bf[3] = {{0,0,0,0,0,0,0,0},{0,0,0,0,0,0,0,0},{0,0,0,0,0,0,0,0}};
        if (q == 0){
            #pragma unroll
            for (int nt=0;nt<3;nt++)
                bf[nt] = *(const half8*)(gF + (nt*16+cl)*FSTR + 64);
        }
        #pragma unroll
        for (int mt=0;mt<4;mt++){
            const half8 af = *(const half8*)(wT + (mt*16+cl)*96 + 64 + q*8);
            #pragma unroll
            for (int nt=0;nt<3;nt++)
                acc[mt][nt] = __builtin_amdgcn_mfma_f32_16x16x32_f16(af, bf[nt], acc[mt][nt], 0,0,0);
        }
    }

    // gelu + pack + store hid^T into the SAME LDS region
    LDS_FENCE();   // all feat reads drained before overwrite
    #pragma unroll
    for (int mt=0;mt<4;mt++){
        #pragma unroll
        for (int nt=0;nt<3;nt++){
            half4 hv = {(f16)gelu_lut(acc[mt][nt][0], lut), (f16)gelu_lut(acc[mt][nt][1], lut),
                        (f16)gelu_lut(acc[mt][nt][2], lut), (f16)gelu_lut(acc[mt][nt][3], lut)};
            *(half4*)(gH + (nt*16+cl)*HSTR + mt*16 + q*4) = hv;
        }
    }

    // ================= Phase 3: PE fold (lane = hidden j) =================
    float pe = g_b1[lane];
    {
        const float inv_n = rsqrtf(dx*dx+dy*dy+dz*dz);
        const float vd0=dx*inv_n, vd1=dy*inv_n, vd2=dz*inv_n;
        pe += vd0*g_w1[64*64+lane] + vd1*g_w1[65*64+lane] + vd2*g_w1[66*64+lane];
        #pragma unroll 1
        for (int fq=0; fq<4; fq++){
            const float fs = (float)(1<<fq);
            float s0,c0,s1,c1,s2,c2;
            __sincosf(vd0*fs, &s0, &c0);
            __sincosf(vd1*fs, &s1, &c1);
            __sincosf(vd2*fs, &s2, &c2);
            pe += s0*g_w1[(67+fq*3+0)*64+lane];
            pe += s1*g_w1[(67+fq*3+1)*64+lane];
            pe += s2*g_w1[(67+fq*3+2)*64+lane];
            pe += c0*g_w1[(79+fq*3+0)*64+lane];
            pe += c1*g_w1[(79+fq*3+1)*64+lane];
            pe += c2*g_w1[(79+fq*3+2)*64+lane];
        }
    }

    // ======== Phase 4: layer-2 GEMM  h2^T(64x48) = w1T(64x64) @ hid^T(64x48) ========
    f32x4 acc2[4][3];
    #pragma unroll
    for (int mt=0;mt<4;mt++){
        const float p0 = __shfl(pe, mt*16+q*4+0, 64);
        const float p1 = __shfl(pe, mt*16+q*4+1, 64);
        const float p2 = __shfl(pe, mt*16+q*4+2, 64);
        const float p3 = __shfl(pe, mt*16+q*4+3, 64);
        #pragma unroll
        for (int nt=0;nt<3;nt++){
            acc2[mt][nt][0]=p0; acc2[mt][nt][1]=p1; acc2[mt][nt][2]=p2; acc2[mt][nt][3]=p3;
        }
    }

    LDS_FENCE();   // hid writes visible

    #pragma unroll 1
    for (int ks=0; ks<2; ks++){
        half8 bf[3];
        #pragma unroll
        for (int nt=0;nt<3;nt++)
            bf[nt] = *(const half8*)(gH + (nt*16+cl)*HSTR + ks*32 + q*8);
        #pragma unroll
        for (int mt=0;mt<4;mt++){
            const half8 af = *(const half8*)(w1T + (mt*16+cl)*64 + ks*32 + q*8);
            #pragma unroll
            for (int nt=0;nt<3;nt++)
                acc2[mt][nt] = __builtin_amdgcn_mfma_f32_16x16x32_f16(af, bf[nt], acc2[mt][nt], 0,0,0);
        }
    }

    // ======== Phase 5: layer 3 + sigmoid, straight from C-registers ========
    const float b20=g_b2[0], b21=g_b2[1], b22=g_b2[2];
    float rgb0=0.0f, rgb1=0.0f, rgb2=0.0f;
    #pragma unroll
    for (int nt=0;nt<3;nt++){
        float r0=0.0f, r1=0.0f, r2=0.0f;
        #pragma unroll
        for (int mt=0;mt<4;mt++){
            const float4* wp = (const float4*)(g_w2 + (size_t)(mt*16+q*4)*3);
            const float4 wa = wp[0], wb = wp[1], wc = wp[2];
            const float g0 = gelu_lut(acc2[mt][nt][0], lut);
            const float g1 = gelu_lut(acc2[mt][nt][1], lut);
            const float g2 = gelu_lut(acc2[mt][nt][2], lut);
            const float g3 = gelu_lut(acc2[mt][nt][3], lut);
            r0 += g0*wa.x + g1*wa.w + g2*wb.z + g3*wc.y;
            r1 += g0*wa.y + g1*wb.x + g2*wb.w + g3*wc.z;
            r2 += g0*wa.z + g1*wb.y + g2*wc.x + g3*wc.w;
        }
        r0 += __shfl_xor(r0, 16, 64);  r0 += __shfl_xor(r0, 32, 64);
        r1 += __shfl_xor(r1, 16, 64);  r1 += __shfl_xor(r1, 32, 64);
        r2 += __shfl_xor(r2, 16, 64);  r2 += __shfl_xor(r2, 32, 64);
        if (q == nt){
            rgb0 = sigmoid_f(r0+b20);
            rgb1 = sigmoid_f(r1+b21);
            rgb2 = sigmoid_f(r2+b22);
        }
    }

    // ======== Phase 6: volume integration (lane = sample) ========
    const float sg    = fmaxf(sigma, 0.0f);
    const float alpha = active ? (1.0f - __expf(-sg*0.03125f)) : 0.0f;
    float v = active ? (1.0f - alpha + 1e-10f) : 1.0f;
    #pragma unroll
    for (int off=1; off<64; off<<=1){
        const float up = __shfl_up(v, off, 64);
        if (lane >= off) v *= up;
    }
    float T = __shfl_up(v, 1, 64);
    if (lane==0) T = 1.0f;
    const float w = alpha*T;

    if (active) out[(size_t)NR*4 + (size_t)ray*NSMP + s] = w;

    float A0=w*rgb0, A1=w*rgb1, A2=w*rgb2, AD=w*mid;
    #pragma unroll
    for (int off=32; off>0; off>>=1){
        A0 += __shfl_down(A0, off, 64);
        A1 += __shfl_down(A1, off, 64);
        A2 += __shfl_down(A2, off, 64);
        AD += __shfl_down(AD, off, 64);
    }
    if (lane==0){
        out[(size_t)ray*3+0]=A0;
        out[(size_t)ray*3+1]=A1;
        out[(size_t)ray*3+2]=A2;
        out[(size_t)NR*3 + (size_t)ray]=AD;
    }
}

// One fused prep kernel:
//  blocks [0, tileN)          : LDS-tiled mats transpose f32 [ib][32][2304] -> f16 [ib][2304][32]
//  blocks [tileN, tileN+prepN): vec transpose + weight prep (linear index)
__global__ __launch_bounds__(256)
void fused_prep(const float* __restrict__ mats, const float* __restrict__ vecs,
                const float* __restrict__ w_mat, const float* __restrict__ w1,
                f16* __restrict__ tm, f16* __restrict__ tv,
                f16* __restrict__ wT, f16* __restrict__ w1T,
                int tileN, int vecsz){
    __shared__ float tl[32][33];
    const int bid = blockIdx.x;
    if (bid < tileN){
        const int ib   = bid / 72;
        const int pix0 = (bid % 72) * 32;
        const int tx = threadIdx.x & 31;
        const int ty = threadIdx.x >> 5;      // 0..7
        const float* src = mats + (size_t)ib*32*2304;
        #pragma unroll
        for (int t=0;t<4;t++){
            const int c = ty + t*8;
            tl[c][tx] = src[(size_t)c*2304 + pix0 + tx];
        }
        __syncthreads();
        f16* dst = tm + (size_t)ib*2304*32;
        #pragma unroll
        for (int t=0;t<4;t++){
            const int p = ty + t*8;
            dst[(size_t)(pix0+p)*32 + tx] = (f16)tl[tx][p];
        }
    } else {
        const int idx = (bid - tileN)*256 + threadIdx.x;
        if (idx < vecsz){
            const int r  = idx % 48;
            const int c  = (idx / 48) & 31;
            const int ib = idx / (48*32);
            tv[((size_t)ib*48+r)*32 + c] = (f16)vecs[idx];
        } else if (idx < vecsz + 64*96){
            const int i1 = idx - vecsz;
            const int n = i1 / 96, k = i1 % 96;
            wT[i1] = (k < 72) ? (f16)w_mat[k*64+n] : (f16)0.0f;
        } else if (idx < vecsz + 64*96 + 64*64){
            const int i2 = idx - vecsz - 64*96;
            const int n = i2 / 64, k = i2 % 64;
            w1T[i2] = (f16)w1[k*64+n];
        }
    }
}

extern "C" void kernel_launch(void* const* d_in, const int* in_sizes, int n_in,
                              void* d_out, int out_size, void* d_ws, size_t ws_size,
                              hipStream_t stream) {
    const float* rays_o  = (const float*)d_in[0];
    const float* rays_d  = (const float*)d_in[1];
    const float* matrixs = (const float*)d_in[2];
    const float* vectors = (const float*)d_in[3];
    const float* w_mat   = (const float*)d_in[4];
    const float* b_mat   = (const float*)d_in[5];
    const float* w1      = (const float*)d_in[6];
    const float* b1      = (const float*)d_in[7];
    const float* w2      = (const float*)d_in[8];
    const float* b2      = (const float*)d_in[9];
    float* out = (float*)d_out;

    const int B = in_sizes[2] / (3*32*48*48);
    const int R = (in_sizes[0]/3) / B;
    const int NR = B*R;

    const int matsz = 3*B*32*2304;
    const int vecsz = 3*B*32*48;
    const size_t need_full = ((size_t)matsz + (size_t)vecsz)*sizeof(f16)
                           + (size_t)(64*96+64*64)*sizeof(f16);
    const size_t need_w    = (size_t)(64*96+64*64)*sizeof(f16);

    const int nblk = (NR + WAVES-1)/WAVES;
    const int nthr = WAVES*64;

    if (ws_size >= need_full){
        f16* tm  = (f16*)d_ws;
        f16* tv  = tm + matsz;
        f16* wT  = tv + vecsz;
        f16* w1T = wT + 64*96;
        const int tileN = 72*3*B;
        const int smalln = vecsz + 64*96 + 64*64;
        const int prepN  = (smalln + 255)/256;
        fused_prep<<<tileN + prepN, 256, 0, stream>>>(matrixs, vectors, w_mat, w1,
                                                      tm, tv, wT, w1T, tileN, vecsz);
        render_kernel<true><<<nblk, nthr, 0, stream>>>(rays_o, rays_d, tm, tv,
            nullptr, nullptr, wT, b_mat, w1T, b1, w1, w2, b2, out, B, R);
    } else if (ws_size >= need_w){
        f16* wT  = (f16*)d_ws;
        f16* w1T = wT + 64*96;
        const int smalln = 64*96 + 64*64;
        fused_prep<<<(smalln+255)/256, 256, 0, stream>>>(nullptr, nullptr, w_mat, w1,
                                                         nullptr, nullptr, wT, w1T, 0, 0);
        render_kernel<false><<<nblk, nthr, 0, stream>>>(rays_o, rays_d,
            nullptr, nullptr, matrixs, vectors, wT, b_mat, w1T, b1, w1, w2, b2, out, B, R);
    }
}

// Round 14
// 279.789 us; speedup vs baseline: 1.0204x; 1.0129x over previous
//
#include <hip/hip_runtime.h>
#include <math.h>

#define NSMP 48
#define FSTR 72    // feat row stride in f16 (72 data, no pad; 144B rows, 2-way banks = free)
#define HSTR 72    // hid row stride in f16 (64 + 8 pad; 144B, 16B-aligned)
#define WAVES 4
#define LUTN 256   // f32 gelu LUT (phase-5 only), [-8,8] step 1/16

typedef _Float16 f16;
typedef _Float16 half8 __attribute__((ext_vector_type(8)));
typedef _Float16 half4 __attribute__((ext_vector_type(4)));
typedef _Float16 h2    __attribute__((ext_vector_type(2)));
typedef float    f32x4 __attribute__((ext_vector_type(4)));

__device__ __forceinline__ float sigmoid_f(float x){
    return __builtin_amdgcn_rcpf(1.0f + __expf(-x));
}
// accurate f32 gelu LUT, slope-intercept form (phase-5 only)
__device__ __forceinline__ float gelu_lut(float x, const float2* __restrict__ lut){
    float u = __builtin_fmaf(x, 16.0f, 128.0f);
    u = fminf(fmaxf(u, 0.0f), 255.0f);
    const float2 e = lut[(int)u];
    return x * __builtin_fmaf(u, e.y, e.x);
}
// fast f16 gelu: Phi-table indexed by top-10 bits of the f16 value (sign+exp+4 mant)
__device__ __forceinline__ h2 gelu16x2(h2 x, const f16* __restrict__ lut16){
    const uint32_t w = __builtin_bit_cast(uint32_t, x);
    h2 m = { lut16[(w>>6) & 0x3FF], lut16[w>>22] };
    return x * m;
}
__device__ __forceinline__ f16 gelu16_1(f16 x, const f16* __restrict__ lut16){
    const uint16_t w = __builtin_bit_cast(uint16_t, x);
    return x * lut16[(w>>6) & 0x3FF];
}
// wave-synchronous LDS fence (per-wave LDS regions)
#define LDS_FENCE() asm volatile("s_waitcnt lgkmcnt(0)" ::: "memory")

template<bool TR>
__global__ __launch_bounds__(WAVES*64, 4)
void render_kernel(const float* __restrict__ rays_o,
                   const float* __restrict__ rays_d,
                   const f16*   __restrict__ mats16,  // TR: [ib][pix][32] f16
                   const f16*   __restrict__ vecs16,  // TR: [ib][r][32] f16
                   const float* __restrict__ matsf,   // !TR: original f32 layout
                   const float* __restrict__ vecsf,
                   const f16*   __restrict__ wT,      // [64][96] f16, 0-pad k>=72
                   const float* __restrict__ g_bmat,
                   const f16*   __restrict__ w1T,     // [64][64] f16
                   const float* __restrict__ g_b1,
                   const float* __restrict__ g_w1,    // f32 w1 (PE rows 64..90)
                   const float* __restrict__ g_w2,
                   const float* __restrict__ g_b2,
                   float* __restrict__ out, int B, int R)
{
    __shared__ f16 s_buf[WAVES][NSMP*FSTR];   // 27648 B (feat, then hid overlays)
    __shared__ float2 s_lut[LUTN];            // 2048 B (phase-5 accurate LUT)
    __shared__ f16 s_lut16[1024];             // 2048 B (f16 Phi table) -> 31744 B total

    const int tid  = threadIdx.x;

    // build both LUTs (block-shared), BEFORE any wave can exit
    for (int i = tid; i < LUTN; i += WAVES*64){
        const float x0 = -8.0f + (float)i * 0.0625f;
        const float p0 = 0.5f*(1.0f + erff( x0          *0.70710678118654752f));
        const float p1 = 0.5f*(1.0f + erff((x0+0.0625f) *0.70710678118654752f));
        const float slope = p1 - p0;
        float2 e; e.y = slope; e.x = p0 - (float)i*slope;
        s_lut[i] = e;
    }
    for (int i = tid; i < 1024; i += WAVES*64){
        const unsigned short bits = (unsigned short)((i<<6) | 0x20);  // bin midpoint
        const f16 xh = __builtin_bit_cast(f16, bits);
        float m;
        if (((i>>4)&0x1F) == 31) m = (i & 0x200) ? 0.0f : 1.0f;       // inf/nan bins
        else {
            const float x = (float)xh;
            m = 0.5f*(1.0f + erff(x*0.70710678118654752f));           // Phi(x)
        }
        s_lut16[i] = (f16)m;
    }
    __syncthreads();
    const float2* lut  = s_lut;
    const f16*   lut16 = s_lut16;

    const int wv   = tid >> 6;
    const int lane = tid & 63;
    const int NR   = B*R;
    const int ray  = blockIdx.x*WAVES + wv;
    if (ray >= NR) return;                    // wave-uniform exit (after barrier)
    const int b = ray / R;

    f16* gF = s_buf[wv];
    f16* gH = s_buf[wv];                      // overlay

    const float ox=rays_o[ray*3+0], oy=rays_o[ray*3+1], oz=rays_o[ray*3+2];
    const float dx=rays_d[ray*3+0], dy=rays_d[ray*3+1], dz=rays_d[ray*3+2];

    // ================= Phase 1: gather (lane = sample) =================
    const int  s      = lane;
    const bool active = (s < NSMP);
    const int  sc     = active ? s : (NSMP-1);
    const float mid   = ((float)s  + 0.5f) * 0.03125f;
    const float midc  = ((float)sc + 0.5f) * 0.03125f;

    const float x0c = 1.25f*(ox + dx*midc);
    const float x1c = 1.25f*(oy + dy*midc);
    const float x2c = 1.25f*(oz + dz*midc);

    float sigma = 0.0f;

    #pragma unroll 1
    for (int i=0;i<3;i++){
        // MAT_MODE = {{0,1},{2,0},{1,2}}, VEC_MODE = {2,1,0}
        const float cx = (i==0)? x0c : (i==1)? x2c : x1c;
        const float cy = (i==0)? x1c : (i==1)? x0c : x2c;
        const float cv = (i==0)? x2c : (i==1)? x1c : x0c;

        const float px = (cx+1.0f)*23.5f;
        const float py = (cy+1.0f)*23.5f;
        const float fx0 = floorf(px), fy0 = floorf(py);
        const float wx = px-fx0, wy = py-fy0;
        const int ix0 = (int)fx0, iy0 = (int)fy0;

        int   toff[4];
        float tw[4];
        #pragma unroll
        for (int t=0;t<4;t++){
            const int xx = ix0 + (t&1);
            const int yy = iy0 + (t>>1);
            const bool inb = (xx>=0)&&(xx<48)&&(yy>=0)&&(yy<48);
            const int xcl = min(max(xx,0),47);
            const int ycl = min(max(yy,0),47);
            toff[t] = ycl*48+xcl;
            const float wxx = (t&1)? wx : 1.0f-wx;
            const float wyy = (t>>1)? wy : 1.0f-wy;
            tw[t] = inb ? wxx*wyy : 0.0f;
        }

        const float pv = (cv+1.0f)*23.5f;
        const float fp0 = floorf(pv);
        const float wvv = pv-fp0;
        const int ip0 = (int)fp0;
        int voff[2]; float vw[2];
        #pragma unroll
        for (int t=0;t<2;t++){
            const int pp = ip0+t;
            const bool inb = (pp>=0)&&(pp<48);
            voff[t] = min(max(pp,0),47);
            vw[t] = inb ? ((t)? wvv : 1.0f-wvv) : 0.0f;
        }

        if (TR){
            const f16* pb = mats16 + ((size_t)(i*B+b))*(2304u*32u);
            const f16* vb = vecs16 + ((size_t)(i*B+b))*(48u*32u);
            const half8* t0 = (const half8*)(pb + toff[0]*32);
            const half8* t1 = (const half8*)(pb + toff[1]*32);
            const half8* t2 = (const half8*)(pb + toff[2]*32);
            const half8* t3 = (const half8*)(pb + toff[3]*32);
            const half8* v0 = (const half8*)(vb + voff[0]*32);
            const half8* v1 = (const half8*)(vb + voff[1]*32);

            const h2 tw0h = {(f16)tw[0],(f16)tw[0]};
            const h2 tw1h = {(f16)tw[1],(f16)tw[1]};
            const h2 tw2h = {(f16)tw[2],(f16)tw[2]};
            const h2 tw3h = {(f16)tw[3],(f16)tw[3]};
            const h2 vw0h = {(f16)vw[0],(f16)vw[0]};
            const h2 vw1h = {(f16)vw[1],(f16)vw[1]};

            // 8 channels per iter, packed-f16 blend + f16-LUT gelu
            #pragma unroll 2
            for (int c4=0;c4<4;c4++){
                const half8 a0=t0[c4], a1=t1[c4], a2=t2[c4], a3=t3[c4];
                const half8 q0=v0[c4], q1=v1[c4];
                h2 gg[4];
                #pragma unroll
                for (int j=0;j<4;j++){
                    const h2 a0j = {a0[2*j], a0[2*j+1]};
                    const h2 a1j = {a1[2*j], a1[2*j+1]};
                    const h2 a2j = {a2[2*j], a2[2*j+1]};
                    const h2 a3j = {a3[2*j], a3[2*j+1]};
                    const h2 q0j = {q0[2*j], q0[2*j+1]};
                    const h2 q1j = {q1[2*j], q1[2*j+1]};
                    h2 pf = a0j*tw0h; pf += a1j*tw1h; pf += a2j*tw2h; pf += a3j*tw3h;
                    h2 vf = q0j*vw0h; vf += q1j*vw1h;
                    const h2 fj = pf*vf;
                    if (c4==0){
                        sigma += (float)fj[0] + (float)fj[1];
                    } else {
                        gg[j] = gelu16x2(fj, lut16);
                    }
                }
                if (c4>0 && active){
                    half8 hv = {gg[0][0],gg[0][1],gg[1][0],gg[1][1],
                                gg[2][0],gg[2][1],gg[3][0],gg[3][1]};
                    *(half8*)(gF + s*FSTR + i*24 + c4*8 - 8) = hv;
                }
            }
        } else {
            const float* pb = matsf + ((size_t)(i*B+b))*(32u*2304u);
            const float* vb = vecsf + ((size_t)(i*B+b))*(32u*48u);
            #pragma unroll 2
            for (int c=0;c<32;c++){
                const float* fc = pb + c*2304;
                const float pf = tw[0]*fc[toff[0]] + tw[1]*fc[toff[1]]
                               + tw[2]*fc[toff[2]] + tw[3]*fc[toff[3]];
                const float* vc = vb + c*48;
                const float vf = vw[0]*vc[voff[0]] + vw[1]*vc[voff[1]];
                const float r = pf*vf;
                if (c < 8) sigma += r;
                else if (active) gF[s*FSTR + i*24 + c - 8] = gelu16_1((f16)r, lut16);
            }
        }
    }
    // no K-pad region: 3rd K-step zeroes its B-frag in registers

    const int q  = lane >> 4;   // quad
    const int cl = lane & 15;   // col index within tile

    // ======== Phase 2: layer-1 GEMM  hid^T(64x48) = wT(64x96) @ feat^T(96x48) ========
    f32x4 acc[4][3];
    #pragma unroll
    for (int mt=0;mt<4;mt++){
        const float4 bmv = *(const float4*)(g_bmat + mt*16 + q*4);
        #pragma unroll
        for (int nt=0;nt<3;nt++){
            acc[mt][nt][0]=bmv.x; acc[mt][nt][1]=bmv.y; acc[mt][nt][2]=bmv.z; acc[mt][nt][3]=bmv.w;
        }
    }

    LDS_FENCE();   // feat writes visible to whole wave

    #pragma unroll 1
    for (int ks=0; ks<2; ks++){
        half8 bf[3];
        #pragma unroll
        for (int nt=0;nt<3;nt++)
            bf[nt] = *(const half8*)(gF + (nt*16+cl)*FSTR + ks*32 + q*8);
        #pragma unroll
        for (int mt=0;mt<4;mt++){
            const half8 af = *(const half8*)(wT + (mt*16+cl)*96 + ks*32 + q*8);
            #pragma unroll
            for (int nt=0;nt<3;nt++)
                acc[mt][nt] = __builtin_amdgcn_mfma_f32_16x16x32_f16(af, bf[nt], acc[mt][nt], 0,0,0);
        }
    }
    {   // ks=2: only q==0 holds real B data (k=64..71); wT rows k>=72 are zero-padded.
        half8 bf[3] = {{0,0,0,0,0,0,0,0},{0,0,0,0,0,0,0,0},{0,0,0,0,0,0,0,0}};
        if (q == 0){
            #pragma unroll
            for (int nt=0;nt<3;nt++)
                bf[nt] = *(const half8*)(gF + (nt*16+cl)*FSTR + 64);
        }
        #pragma unroll
        for (int mt=0;mt<4;mt++){
            const half8 af = *(const half8*)(wT + (mt*16+cl)*96 + 64 + q*8);
            #pragma unroll
            for (int nt=0;nt<3;nt++)
                acc[mt][nt] = __builtin_amdgcn_mfma_f32_16x16x32_f16(af, bf[nt], acc[mt][nt], 0,0,0);
        }
    }

    // gelu (f16 LUT, via pack-cvt) + store hid^T into the SAME LDS region
    LDS_FENCE();   // all feat reads drained before overwrite
    #pragma unroll
    for (int mt=0;mt<4;mt++){
        #pragma unroll
        for (int nt=0;nt<3;nt++){
            const h2 p01 = __builtin_bit_cast(h2,
                __builtin_amdgcn_cvt_pkrtz(acc[mt][nt][0], acc[mt][nt][1]));
            const h2 p23 = __builtin_bit_cast(h2,
                __builtin_amdgcn_cvt_pkrtz(acc[mt][nt][2], acc[mt][nt][3]));
            const h2 g01 = gelu16x2(p01, lut16);
            const h2 g23 = gelu16x2(p23, lut16);
            half4 hv = {g01[0], g01[1], g23[0], g23[1]};
            *(half4*)(gH + (nt*16+cl)*HSTR + mt*16 + q*4) = hv;
        }
    }

    // ================= Phase 3: PE fold (lane = hidden j) =================
    float pe = g_b1[lane];
    {
        const float inv_n = rsqrtf(dx*dx+dy*dy+dz*dz);
        const float vd0=dx*inv_n, vd1=dy*inv_n, vd2=dz*inv_n;
        pe += vd0*g_w1[64*64+lane] + vd1*g_w1[65*64+lane] + vd2*g_w1[66*64+lane];
        #pragma unroll 1
        for (int fq=0; fq<4; fq++){
            const float fs = (float)(1<<fq);
            float s0,c0,s1,c1,s2,c2;
            __sincosf(vd0*fs, &s0, &c0);
            __sincosf(vd1*fs, &s1, &c1);
            __sincosf(vd2*fs, &s2, &c2);
            pe += s0*g_w1[(67+fq*3+0)*64+lane];
            pe += s1*g_w1[(67+fq*3+1)*64+lane];
            pe += s2*g_w1[(67+fq*3+2)*64+lane];
            pe += c0*g_w1[(79+fq*3+0)*64+lane];
            pe += c1*g_w1[(79+fq*3+1)*64+lane];
            pe += c2*g_w1[(79+fq*3+2)*64+lane];
        }
    }

    // ======== Phase 4: layer-2 GEMM  h2^T(64x48) = w1T(64x64) @ hid^T(64x48) ========
    f32x4 acc2[4][3];
    #pragma unroll
    for (int mt=0;mt<4;mt++){
        const float p0 = __shfl(pe, mt*16+q*4+0, 64);
        const float p1 = __shfl(pe, mt*16+q*4+1, 64);
        const float p2 = __shfl(pe, mt*16+q*4+2, 64);
        const float p3 = __shfl(pe, mt*16+q*4+3, 64);
        #pragma unroll
        for (int nt=0;nt<3;nt++){
            acc2[mt][nt][0]=p0; acc2[mt][nt][1]=p1; acc2[mt][nt][2]=p2; acc2[mt][nt][3]=p3;
        }
    }

    LDS_FENCE();   // hid writes visible

    #pragma unroll 1
    for (int ks=0; ks<2; ks++){
        half8 bf[3];
        #pragma unroll
        for (int nt=0;nt<3;nt++)
            bf[nt] = *(const half8*)(gH + (nt*16+cl)*HSTR + ks*32 + q*8);
        #pragma unroll
        for (int mt=0;mt<4;mt++){
            const half8 af = *(const half8*)(w1T + (mt*16+cl)*64 + ks*32 + q*8);
            #pragma unroll
            for (int nt=0;nt<3;nt++)
                acc2[mt][nt] = __builtin_amdgcn_mfma_f32_16x16x32_f16(af, bf[nt], acc2[mt][nt], 0,0,0);
        }
    }

    // ======== Phase 5: layer 3 + sigmoid (accurate f32 LUT) ========
    const float b20=g_b2[0], b21=g_b2[1], b22=g_b2[2];
    float rgb0=0.0f, rgb1=0.0f, rgb2=0.0f;
    #pragma unroll
    for (int nt=0;nt<3;nt++){
        float r0=0.0f, r1=0.0f, r2=0.0f;
        #pragma unroll
        for (int mt=0;mt<4;mt++){
            const float4* wp = (const float4*)(g_w2 + (size_t)(mt*16+q*4)*3);
            const float4 wa = wp[0], wb = wp[1], wc = wp[2];
            const float g0 = gelu_lut(acc2[mt][nt][0], lut);
            const float g1 = gelu_lut(acc2[mt][nt][1], lut);
            const float g2 = gelu_lut(acc2[mt][nt][2], lut);
            const float g3 = gelu_lut(acc2[mt][nt][3], lut);
            r0 += g0*wa.x + g1*wa.w + g2*wb.z + g3*wc.y;
            r1 += g0*wa.y + g1*wb.x + g2*wb.w + g3*wc.z;
            r2 += g0*wa.z + g1*wb.y + g2*wc.x + g3*wc.w;
        }
        r0 += __shfl_xor(r0, 16, 64);  r0 += __shfl_xor(r0, 32, 64);
        r1 += __shfl_xor(r1, 16, 64);  r1 += __shfl_xor(r1, 32, 64);
        r2 += __shfl_xor(r2, 16, 64);  r2 += __shfl_xor(r2, 32, 64);
        if (q == nt){
            rgb0 = sigmoid_f(r0+b20);
            rgb1 = sigmoid_f(r1+b21);
            rgb2 = sigmoid_f(r2+b22);
        }
    }

    // ======== Phase 6: volume integration (lane = sample) ========
    const float sg    = fmaxf(sigma, 0.0f);
    const float alpha = active ? (1.0f - __expf(-sg*0.03125f)) : 0.0f;
    float v = active ? (1.0f - alpha + 1e-10f) : 1.0f;
    #pragma unroll
    for (int off=1; off<64; off<<=1){
        const float up = __shfl_up(v, off, 64);
        if (lane >= off) v *= up;
    }
    float T = __shfl_up(v, 1, 64);
    if (lane==0) T = 1.0f;
    const float w = alpha*T;

    if (active) out[(size_t)NR*4 + (size_t)ray*NSMP + s] = w;

    float A0=w*rgb0, A1=w*rgb1, A2=w*rgb2, AD=w*mid;
    #pragma unroll
    for (int off=32; off>0; off>>=1){
        A0 += __shfl_down(A0, off, 64);
        A1 += __shfl_down(A1, off, 64);
        A2 += __shfl_down(A2, off, 64);
        AD += __shfl_down(AD, off, 64);
    }
    if (lane==0){
        out[(size_t)ray*3+0]=A0;
        out[(size_t)ray*3+1]=A1;
        out[(size_t)ray*3+2]=A2;
        out[(size_t)NR*3 + (size_t)ray]=AD;
    }
}

// One fused prep kernel:
//  blocks [0, tileN)          : LDS-tiled mats transpose f32 [ib][32][2304] -> f16 [ib][2304][32]
//  blocks [tileN, tileN+prepN): vec transpose + weight prep (linear index)
__global__ __launch_bounds__(256)
void fused_prep(const float* __restrict__ mats, const float* __restrict__ vecs,
                const float* __restrict__ w_mat, const float* __restrict__ w1,
                f16* __restrict__ tm, f16* __restrict__ tv,
                f16* __restrict__ wT, f16* __restrict__ w1T,
                int tileN, int vecsz){
    __shared__ float tl[32][33];
    const int bid = blockIdx.x;
    if (bid < tileN){
        const int ib   = bid / 72;
        const int pix0 = (bid % 72) * 32;
        const int tx = threadIdx.x & 31;
        const int ty = threadIdx.x >> 5;      // 0..7
        const float* src = mats + (size_t)ib*32*2304;
        #pragma unroll
        for (int t=0;t<4;t++){
            const int c = ty + t*8;
            tl[c][tx] = src[(size_t)c*2304 + pix0 + tx];
        }
        __syncthreads();
        f16* dst = tm + (size_t)ib*2304*32;
        #pragma unroll
        for (int t=0;t<4;t++){
            const int p = ty + t*8;
            dst[(size_t)(pix0+p)*32 + tx] = (f16)tl[tx][p];
        }
    } else {
        const int idx = (bid - tileN)*256 + threadIdx.x;
        if (idx < vecsz){
            const int r  = idx % 48;
            const int c  = (idx / 48) & 31;
            const int ib = idx / (48*32);
            tv[((size_t)ib*48+r)*32 + c] = (f16)vecs[idx];
        } else if (idx < vecsz + 64*96){
            const int i1 = idx - vecsz;
            const int n = i1 / 96, k = i1 % 96;
            wT[i1] = (k < 72) ? (f16)w_mat[k*64+n] : (f16)0.0f;
        } else if (idx < vecsz + 64*96 + 64*64){
            const int i2 = idx - vecsz - 64*96;
            const int n = i2 / 64, k = i2 % 64;
            w1T[i2] = (f16)w1[k*64+n];
        }
    }
}

extern "C" void kernel_launch(void* const* d_in, const int* in_sizes, int n_in,
                              void* d_out, int out_size, void* d_ws, size_t ws_size,
                              hipStream_t stream) {
    const float* rays_o  = (const float*)d_in[0];
    const float* rays_d  = (const float*)d_in[1];
    const float* matrixs = (const float*)d_in[2];
    const float* vectors = (const float*)d_in[3];
    const float* w_mat   = (const float*)d_in[4];
    const float* b_mat   = (const float*)d_in[5];
    const float* w1      = (const float*)d_in[6];
    const float* b1      = (const float*)d_in[7];
    const float* w2      = (const float*)d_in[8];
    const float* b2      = (const float*)d_in[9];
    float* out = (float*)d_out;

    const int B = in_sizes[2] / (3*32*48*48);
    const int R = (in_sizes[0]/3) / B;
    const int NR = B*R;

    const int matsz = 3*B*32*2304;
    const int vecsz = 3*B*32*48;
    const size_t need_full = ((size_t)matsz + (size_t)vecsz)*sizeof(f16)
                           + (size_t)(64*96+64*64)*sizeof(f16);
    const size_t need_w    = (size_t)(64*96+64*64)*sizeof(f16);

    const int nblk = (NR + WAVES-1)/WAVES;
    const int nthr = WAVES*64;

    if (ws_size >= need_full){
        f16* tm  = (f16*)d_ws;
        f16* tv  = tm + matsz;
        f16* wT  = tv + vecsz;
        f16* w1T = wT + 64*96;
        const int tileN = 72*3*B;
        const int smalln = vecsz + 64*96 + 64*64;
        const int prepN  = (smalln + 255)/256;
        fused_prep<<<tileN + prepN, 256, 0, stream>>>(matrixs, vectors, w_mat, w1,
                                                      tm, tv, wT, w1T, tileN, vecsz);
        render_kernel<true><<<nblk, nthr, 0, stream>>>(rays_o, rays_d, tm, tv,
            nullptr, nullptr, wT, b_mat, w1T, b1, w1, w2, b2, out, B, R);
    } else if (ws_size >= need_w){
        f16* wT  = (f16*)d_ws;
        f16* w1T = wT + 64*96;
        const int smalln = 64*96 + 64*64;
        fused_prep<<<(smalln+255)/256, 256, 0, stream>>>(nullptr, nullptr, w_mat, w1,
                                                         nullptr, nullptr, wT, w1T, 0, 0);
        render_kernel<false><<<nblk, nthr, 0, stream>>>(rays_o, rays_d,
            nullptr, nullptr, matrixs, vectors, wT, b_mat, w1T, b1, w1, w2, b2, out, B, R);
    }
}

// Round 15
// 255.567 us; speedup vs baseline: 1.1172x; 1.0948x over previous
//
#include <hip/hip_runtime.h>
#include <math.h>

#define NSMP 48
#define FSTR 72    // feat row stride in f16 (72 data, no pad; 144B rows, 2-way banks = free)
#define HSTR 72    // hid row stride in f16 (64 + 8 pad; 144B, 16B-aligned)
#define WAVES 4

typedef _Float16 f16;
typedef _Float16 half8 __attribute__((ext_vector_type(8)));
typedef _Float16 half4 __attribute__((ext_vector_type(4)));
typedef _Float16 h2    __attribute__((ext_vector_type(2)));
typedef float    f32x4 __attribute__((ext_vector_type(4)));

__device__ __forceinline__ float sigmoid_f(float x){
    return __builtin_amdgcn_rcpf(1.0f + __expf(-x));
}
// fast f16 gelu: Phi-table indexed by top-10 bits of the f16 value (sign+exp+4 mant)
__device__ __forceinline__ h2 gelu16x2(h2 x, const f16* __restrict__ lut16){
    const uint32_t w = __builtin_bit_cast(uint32_t, x);
    h2 m = { lut16[(w>>6) & 0x3FF], lut16[w>>22] };
    return x * m;
}
__device__ __forceinline__ f16 gelu16_1(f16 x, const f16* __restrict__ lut16){
    const uint16_t w = __builtin_bit_cast(uint16_t, x);
    return x * lut16[(w>>6) & 0x3FF];
}
// wave-synchronous LDS fence (per-wave LDS regions)
#define LDS_FENCE() asm volatile("s_waitcnt lgkmcnt(0)" ::: "memory")

template<bool TR>
__global__ __launch_bounds__(WAVES*64, 4)
void render_kernel(const float* __restrict__ rays_o,
                   const float* __restrict__ rays_d,
                   const f16*   __restrict__ mats16,  // TR: [ib][pix][32] f16
                   const f16*   __restrict__ vecs16,  // TR: [ib][r][32] f16
                   const float* __restrict__ matsf,   // !TR: original f32 layout
                   const float* __restrict__ vecsf,
                   const f16*   __restrict__ wT,      // [64][96] f16, 0-pad k>=72
                   const float* __restrict__ g_bmat,
                   const f16*   __restrict__ w1T,     // [64][64] f16
                   const float* __restrict__ g_b1,
                   const float* __restrict__ g_w1,    // f32 w1 (PE rows 64..90)
                   const f16*   __restrict__ w2T16,   // [16][64] f16: rows 0..2 = w2^T, rest 0
                   const float* __restrict__ g_b2,
                   float* __restrict__ out, int B, int R)
{
    __shared__ f16 s_buf[WAVES][NSMP*FSTR];   // 27648 B (feat, then hid overlays, then gelu(h2))
    __shared__ f16 s_lut16[1024];             // 2048 B (f16 Phi table) -> 29696 B total

    const int tid  = threadIdx.x;

    // build Phi LUT (block-shared), BEFORE any wave can exit
    for (int i = tid; i < 1024; i += WAVES*64){
        const unsigned short bits = (unsigned short)((i<<6) | 0x20);  // bin midpoint
        const f16 xh = __builtin_bit_cast(f16, bits);
        float m;
        if (((i>>4)&0x1F) == 31) m = (i & 0x200) ? 0.0f : 1.0f;       // inf/nan bins
        else {
            const float x = (float)xh;
            m = 0.5f*(1.0f + erff(x*0.70710678118654752f));           // Phi(x)
        }
        s_lut16[i] = (f16)m;
    }
    __syncthreads();
    const f16* lut16 = s_lut16;

    const int wv   = tid >> 6;
    const int lane = tid & 63;
    const int NR   = B*R;
    const int ray  = blockIdx.x*WAVES + wv;
    if (ray >= NR) return;                    // wave-uniform exit (after barrier)
    const int b = ray / R;

    f16* gF = s_buf[wv];
    f16* gH = s_buf[wv];                      // overlay

    const float ox=rays_o[ray*3+0], oy=rays_o[ray*3+1], oz=rays_o[ray*3+2];
    const float dx=rays_d[ray*3+0], dy=rays_d[ray*3+1], dz=rays_d[ray*3+2];

    // ================= Phase 1: gather (lane = sample) =================
    const int  s      = lane;
    const bool active = (s < NSMP);
    const int  sc     = active ? s : (NSMP-1);
    const float mid   = ((float)s  + 0.5f) * 0.03125f;
    const float midc  = ((float)sc + 0.5f) * 0.03125f;

    const float x0c = 1.25f*(ox + dx*midc);
    const float x1c = 1.25f*(oy + dy*midc);
    const float x2c = 1.25f*(oz + dz*midc);

    float sigma = 0.0f;

    #pragma unroll 1
    for (int i=0;i<3;i++){
        // MAT_MODE = {{0,1},{2,0},{1,2}}, VEC_MODE = {2,1,0}
        const float cx = (i==0)? x0c : (i==1)? x2c : x1c;
        const float cy = (i==0)? x1c : (i==1)? x0c : x2c;
        const float cv = (i==0)? x2c : (i==1)? x1c : x0c;

        const float px = (cx+1.0f)*23.5f;
        const float py = (cy+1.0f)*23.5f;
        const float fx0 = floorf(px), fy0 = floorf(py);
        const float wx = px-fx0, wy = py-fy0;
        const int ix0 = (int)fx0, iy0 = (int)fy0;

        int   toff[4];
        float tw[4];
        #pragma unroll
        for (int t=0;t<4;t++){
            const int xx = ix0 + (t&1);
            const int yy = iy0 + (t>>1);
            const bool inb = (xx>=0)&&(xx<48)&&(yy>=0)&&(yy<48);
            const int xcl = min(max(xx,0),47);
            const int ycl = min(max(yy,0),47);
            toff[t] = ycl*48+xcl;
            const float wxx = (t&1)? wx : 1.0f-wx;
            const float wyy = (t>>1)? wy : 1.0f-wy;
            tw[t] = inb ? wxx*wyy : 0.0f;
        }

        const float pv = (cv+1.0f)*23.5f;
        const float fp0 = floorf(pv);
        const float wvv = pv-fp0;
        const int ip0 = (int)fp0;
        int voff[2]; float vw[2];
        #pragma unroll
        for (int t=0;t<2;t++){
            const int pp = ip0+t;
            const bool inb = (pp>=0)&&(pp<48);
            voff[t] = min(max(pp,0),47);
            vw[t] = inb ? ((t)? wvv : 1.0f-wvv) : 0.0f;
        }

        if (TR){
            const f16* pb = mats16 + ((size_t)(i*B+b))*(2304u*32u);
            const f16* vb = vecs16 + ((size_t)(i*B+b))*(48u*32u);
            const half8* t0 = (const half8*)(pb + toff[0]*32);
            const half8* t1 = (const half8*)(pb + toff[1]*32);
            const half8* t2 = (const half8*)(pb + toff[2]*32);
            const half8* t3 = (const half8*)(pb + toff[3]*32);
            const half8* v0 = (const half8*)(vb + voff[0]*32);
            const half8* v1 = (const half8*)(vb + voff[1]*32);

            const h2 tw0h = {(f16)tw[0],(f16)tw[0]};
            const h2 tw1h = {(f16)tw[1],(f16)tw[1]};
            const h2 tw2h = {(f16)tw[2],(f16)tw[2]};
            const h2 tw3h = {(f16)tw[3],(f16)tw[3]};
            const h2 vw0h = {(f16)vw[0],(f16)vw[0]};
            const h2 vw1h = {(f16)vw[1],(f16)vw[1]};

            // 8 channels per iter, packed-f16 blend + f16-LUT gelu
            #pragma unroll 2
            for (int c4=0;c4<4;c4++){
                const half8 a0=t0[c4], a1=t1[c4], a2=t2[c4], a3=t3[c4];
                const half8 q0=v0[c4], q1=v1[c4];
                h2 gg[4];
                #pragma unroll
                for (int j=0;j<4;j++){
                    const h2 a0j = {a0[2*j], a0[2*j+1]};
                    const h2 a1j = {a1[2*j], a1[2*j+1]};
                    const h2 a2j = {a2[2*j], a2[2*j+1]};
                    const h2 a3j = {a3[2*j], a3[2*j+1]};
                    const h2 q0j = {q0[2*j], q0[2*j+1]};
                    const h2 q1j = {q1[2*j], q1[2*j+1]};
                    h2 pf = a0j*tw0h; pf += a1j*tw1h; pf += a2j*tw2h; pf += a3j*tw3h;
                    h2 vf = q0j*vw0h; vf += q1j*vw1h;
                    const h2 fj = pf*vf;
                    if (c4==0){
                        sigma += (float)fj[0] + (float)fj[1];
                    } else {
                        gg[j] = gelu16x2(fj, lut16);
                    }
                }
                if (c4>0 && active){
                    half8 hv = {gg[0][0],gg[0][1],gg[1][0],gg[1][1],
                                gg[2][0],gg[2][1],gg[3][0],gg[3][1]};
                    *(half8*)(gF + s*FSTR + i*24 + c4*8 - 8) = hv;
                }
            }
        } else {
            const float* pb = matsf + ((size_t)(i*B+b))*(32u*2304u);
            const float* vb = vecsf + ((size_t)(i*B+b))*(32u*48u);
            #pragma unroll 2
            for (int c=0;c<32;c++){
                const float* fc = pb + c*2304;
                const float pf = tw[0]*fc[toff[0]] + tw[1]*fc[toff[1]]
                               + tw[2]*fc[toff[2]] + tw[3]*fc[toff[3]];
                const float* vc = vb + c*48;
                const float vf = vw[0]*vc[voff[0]] + vw[1]*vc[voff[1]];
                const float r = pf*vf;
                if (c < 8) sigma += r;
                else if (active) gF[s*FSTR + i*24 + c - 8] = gelu16_1((f16)r, lut16);
            }
        }
    }

    const int q  = lane >> 4;   // quad
    const int cl = lane & 15;   // col index within tile

    // ======== Phase 2: layer-1 GEMM  hid^T(64x48) = wT(64x96) @ feat^T(96x48) ========
    f32x4 acc[4][3];
    #pragma unroll
    for (int mt=0;mt<4;mt++){
        const float4 bmv = *(const float4*)(g_bmat + mt*16 + q*4);
        #pragma unroll
        for (int nt=0;nt<3;nt++){
            acc[mt][nt][0]=bmv.x; acc[mt][nt][1]=bmv.y; acc[mt][nt][2]=bmv.z; acc[mt][nt][3]=bmv.w;
        }
    }

    LDS_FENCE();   // feat writes visible to whole wave

    #pragma unroll 1
    for (int ks=0; ks<2; ks++){
        half8 bf[3];
        #pragma unroll
        for (int nt=0;nt<3;nt++)
            bf[nt] = *(const half8*)(gF + (nt*16+cl)*FSTR + ks*32 + q*8);
        #pragma unroll
        for (int mt=0;mt<4;mt++){
            const half8 af = *(const half8*)(wT + (mt*16+cl)*96 + ks*32 + q*8);
            #pragma unroll
            for (int nt=0;nt<3;nt++)
                acc[mt][nt] = __builtin_amdgcn_mfma_f32_16x16x32_f16(af, bf[nt], acc[mt][nt], 0,0,0);
        }
    }
    {   // ks=2: only q==0 holds real B data (k=64..71); wT rows k>=72 are zero-padded.
        half8 bf[3] = {{0,0,0,0,0,0,0,0},{0,0,0,0,0,0,0,0},{0,0,0,0,0,0,0,0}};
        if (q == 0){
            #pragma unroll
            for (int nt=0;nt<3;nt++)
                bf[nt] = *(const half8*)(gF + (nt*16+cl)*FSTR + 64);
        }
        #pragma unroll
        for (int mt=0;mt<4;mt++){
            const half8 af = *(const half8*)(wT + (mt*16+cl)*96 + 64 + q*8);
            #pragma unroll
            for (int nt=0;nt<3;nt++)
                acc[mt][nt] = __builtin_amdgcn_mfma_f32_16x16x32_f16(af, bf[nt], acc[mt][nt], 0,0,0);
        }
    }

    // gelu (f16 LUT, via pack-cvt) + store hid^T into the SAME LDS region
    LDS_FENCE();   // all feat reads drained before overwrite
    #pragma unroll
    for (int mt=0;mt<4;mt++){
        #pragma unroll
        for (int nt=0;nt<3;nt++){
            const h2 p01 = __builtin_bit_cast(h2,
                __builtin_amdgcn_cvt_pkrtz(acc[mt][nt][0], acc[mt][nt][1]));
            const h2 p23 = __builtin_bit_cast(h2,
                __builtin_amdgcn_cvt_pkrtz(acc[mt][nt][2], acc[mt][nt][3]));
            const h2 g01 = gelu16x2(p01, lut16);
            const h2 g23 = gelu16x2(p23, lut16);
            half4 hv = {g01[0], g01[1], g23[0], g23[1]};
            *(half4*)(gH + (nt*16+cl)*HSTR + mt*16 + q*4) = hv;
        }
    }

    // ================= Phase 3: PE fold (lane = hidden j) =================
    float pe = g_b1[lane];
    {
        const float inv_n = rsqrtf(dx*dx+dy*dy+dz*dz);
        const float vd0=dx*inv_n, vd1=dy*inv_n, vd2=dz*inv_n;
        pe += vd0*g_w1[64*64+lane] + vd1*g_w1[65*64+lane] + vd2*g_w1[66*64+lane];
        #pragma unroll 1
        for (int fq=0; fq<4; fq++){
            const float fs = (float)(1<<fq);
            float s0,c0,s1,c1,s2,c2;
            __sincosf(vd0*fs, &s0, &c0);
            __sincosf(vd1*fs, &s1, &c1);
            __sincosf(vd2*fs, &s2, &c2);
            pe += s0*g_w1[(67+fq*3+0)*64+lane];
            pe += s1*g_w1[(67+fq*3+1)*64+lane];
            pe += s2*g_w1[(67+fq*3+2)*64+lane];
            pe += c0*g_w1[(79+fq*3+0)*64+lane];
            pe += c1*g_w1[(79+fq*3+1)*64+lane];
            pe += c2*g_w1[(79+fq*3+2)*64+lane];
        }
    }

    // ======== Phase 4: layer-2 GEMM  h2^T(64x48) = w1T(64x64) @ hid^T(64x48) ========
    f32x4 acc2[4][3];
    #pragma unroll
    for (int mt=0;mt<4;mt++){
        const float p0 = __shfl(pe, mt*16+q*4+0, 64);
        const float p1 = __shfl(pe, mt*16+q*4+1, 64);
        const float p2 = __shfl(pe, mt*16+q*4+2, 64);
        const float p3 = __shfl(pe, mt*16+q*4+3, 64);
        #pragma unroll
        for (int nt=0;nt<3;nt++){
            acc2[mt][nt][0]=p0; acc2[mt][nt][1]=p1; acc2[mt][nt][2]=p2; acc2[mt][nt][3]=p3;
        }
    }

    LDS_FENCE();   // hid writes visible

    #pragma unroll 1
    for (int ks=0; ks<2; ks++){
        half8 bf[3];
        #pragma unroll
        for (int nt=0;nt<3;nt++)
            bf[nt] = *(const half8*)(gH + (nt*16+cl)*HSTR + ks*32 + q*8);
        #pragma unroll
        for (int mt=0;mt<4;mt++){
            const half8 af = *(const half8*)(w1T + (mt*16+cl)*64 + ks*32 + q*8);
            #pragma unroll
            for (int nt=0;nt<3;nt++)
                acc2[mt][nt] = __builtin_amdgcn_mfma_f32_16x16x32_f16(af, bf[nt], acc2[mt][nt], 0,0,0);
        }
    }

    // ======== Phase 5: layer 3 via MFMA  rgb^T(16x48) = w2T16(16x64) @ gelu(h2)^T(64x48) ========
    LDS_FENCE();   // phase-4 hid reads drained before overwrite
    // store gelu(h2) into the same region, same [sample][hidden] layout
    #pragma unroll
    for (int mt=0;mt<4;mt++){
        #pragma unroll
        for (int nt=0;nt<3;nt++){
            const h2 p01 = __builtin_bit_cast(h2,
                __builtin_amdgcn_cvt_pkrtz(acc2[mt][nt][0], acc2[mt][nt][1]));
            const h2 p23 = __builtin_bit_cast(h2,
                __builtin_amdgcn_cvt_pkrtz(acc2[mt][nt][2], acc2[mt][nt][3]));
            const h2 g01 = gelu16x2(p01, lut16);
            const h2 g23 = gelu16x2(p23, lut16);
            half4 hv = {g01[0], g01[1], g23[0], g23[1]};
            *(half4*)(gH + (nt*16+cl)*HSTR + mt*16 + q*4) = hv;
        }
    }

    const float b20=g_b2[0], b21=g_b2[1], b22=g_b2[2];
    f32x4 acc3[3];
    #pragma unroll
    for (int nt=0;nt<3;nt++){
        acc3[nt][0] = (q==0)? b20 : 0.0f;
        acc3[nt][1] = (q==0)? b21 : 0.0f;
        acc3[nt][2] = (q==0)? b22 : 0.0f;
        acc3[nt][3] = 0.0f;
    }

    LDS_FENCE();   // gelu(h2) visible

    #pragma unroll 1
    for (int ks=0; ks<2; ks++){
        const half8 af = *(const half8*)(w2T16 + cl*64 + ks*32 + q*8);
        #pragma unroll
        for (int nt=0;nt<3;nt++){
            const half8 bf = *(const half8*)(gH + (nt*16+cl)*HSTR + ks*32 + q*8);
            acc3[nt] = __builtin_amdgcn_mfma_f32_16x16x32_f16(af, bf, acc3[nt], 0,0,0);
        }
    }

    // redistribute: lane L's sample rgb sits in lane (L&15) of tile (L>>4), rows 0..2
    float rgb0, rgb1, rgb2;
    {
        float t[3];
        #pragma unroll
        for (int r=0;r<3;r++){
            const float u0 = __shfl(acc3[0][r], cl, 64);
            const float u1 = __shfl(acc3[1][r], cl, 64);
            const float u2 = __shfl(acc3[2][r], cl, 64);
            t[r] = (q==0)? u0 : (q==1)? u1 : u2;
        }
        rgb0 = sigmoid_f(t[0]);
        rgb1 = sigmoid_f(t[1]);
        rgb2 = sigmoid_f(t[2]);
    }

    // ======== Phase 6: volume integration (lane = sample) ========
    const float sg    = fmaxf(sigma, 0.0f);
    const float alpha = active ? (1.0f - __expf(-sg*0.03125f)) : 0.0f;
    float v = active ? (1.0f - alpha + 1e-10f) : 1.0f;
    #pragma unroll
    for (int off=1; off<64; off<<=1){
        const float up = __shfl_up(v, off, 64);
        if (lane >= off) v *= up;
    }
    float T = __shfl_up(v, 1, 64);
    if (lane==0) T = 1.0f;
    const float w = alpha*T;

    if (active) out[(size_t)NR*4 + (size_t)ray*NSMP + s] = w;

    float A0=w*rgb0, A1=w*rgb1, A2=w*rgb2, AD=w*mid;
    #pragma unroll
    for (int off=32; off>0; off>>=1){
        A0 += __shfl_down(A0, off, 64);
        A1 += __shfl_down(A1, off, 64);
        A2 += __shfl_down(A2, off, 64);
        AD += __shfl_down(AD, off, 64);
    }
    if (lane==0){
        out[(size_t)ray*3+0]=A0;
        out[(size_t)ray*3+1]=A1;
        out[(size_t)ray*3+2]=A2;
        out[(size_t)NR*3 + (size_t)ray]=AD;
    }
}

// One fused prep kernel:
//  blocks [0, tileN)          : LDS-tiled mats transpose f32 [ib][32][2304] -> f16 [ib][2304][32]
//  blocks [tileN, tileN+prepN): vec transpose + weight prep (linear index)
__global__ __launch_bounds__(256)
void fused_prep(const float* __restrict__ mats, const float* __restrict__ vecs,
                const float* __restrict__ w_mat, const float* __restrict__ w1,
                const float* __restrict__ w2,
                f16* __restrict__ tm, f16* __restrict__ tv,
                f16* __restrict__ wT, f16* __restrict__ w1T, f16* __restrict__ w2T16,
                int tileN, int vecsz){
    __shared__ float tl[32][33];
    const int bid = blockIdx.x;
    if (bid < tileN){
        const int ib   = bid / 72;
        const int pix0 = (bid % 72) * 32;
        const int tx = threadIdx.x & 31;
        const int ty = threadIdx.x >> 5;      // 0..7
        const float* src = mats + (size_t)ib*32*2304;
        #pragma unroll
        for (int t=0;t<4;t++){
            const int c = ty + t*8;
            tl[c][tx] = src[(size_t)c*2304 + pix0 + tx];
        }
        __syncthreads();
        f16* dst = tm + (size_t)ib*2304*32;
        #pragma unroll
        for (int t=0;t<4;t++){
            const int p = ty + t*8;
            dst[(size_t)(pix0+p)*32 + tx] = (f16)tl[tx][p];
        }
    } else {
        const int idx = (bid - tileN)*256 + threadIdx.x;
        if (idx < vecsz){
            const int r  = idx % 48;
            const int c  = (idx / 48) & 31;
            const int ib = idx / (48*32);
            tv[((size_t)ib*48+r)*32 + c] = (f16)vecs[idx];
        } else if (idx < vecsz + 64*96){
            const int i1 = idx - vecsz;
            const int n = i1 / 96, k = i1 % 96;
            wT[i1] = (k < 72) ? (f16)w_mat[k*64+n] : (f16)0.0f;
        } else if (idx < vecsz + 64*96 + 64*64){
            const int i2 = idx - vecsz - 64*96;
            const int n = i2 / 64, k = i2 % 64;
            w1T[i2] = (f16)w1[k*64+n];
        } else if (idx < vecsz + 64*96 + 64*64 + 16*64){
            const int i3 = idx - vecsz - 64*96 - 64*64;
            const int n = i3 / 64, k = i3 % 64;
            w2T16[i3] = (n < 3) ? (f16)w2[k*3+n] : (f16)0.0f;
        }
    }
}

extern "C" void kernel_launch(void* const* d_in, const int* in_sizes, int n_in,
                              void* d_out, int out_size, void* d_ws, size_t ws_size,
                              hipStream_t stream) {
    const float* rays_o  = (const float*)d_in[0];
    const float* rays_d  = (const float*)d_in[1];
    const float* matrixs = (const float*)d_in[2];
    const float* vectors = (const float*)d_in[3];
    const float* w_mat   = (const float*)d_in[4];
    const float* b_mat   = (const float*)d_in[5];
    const float* w1      = (const float*)d_in[6];
    const float* b1      = (const float*)d_in[7];
    const float* w2      = (const float*)d_in[8];
    const float* b2      = (const float*)d_in[9];
    float* out = (float*)d_out;

    const int B = in_sizes[2] / (3*32*48*48);
    const int R = (in_sizes[0]/3) / B;
    const int NR = B*R;

    const int matsz = 3*B*32*2304;
    const int vecsz = 3*B*32*48;
    const int wtot  = 64*96 + 64*64 + 16*64;
    const size_t need_full = ((size_t)matsz + (size_t)vecsz + (size_t)wtot)*sizeof(f16);
    const size_t need_w    = (size_t)wtot*sizeof(f16);

    const int nblk = (NR + WAVES-1)/WAVES;
    const int nthr = WAVES*64;

    if (ws_size >= need_full){
        f16* tm    = (f16*)d_ws;
        f16* tv    = tm + matsz;
        f16* wT    = tv + vecsz;
        f16* w1T   = wT + 64*96;
        f16* w2T16 = w1T + 64*64;
        const int tileN = 72*3*B;
        const int smalln = vecsz + wtot;
        const int prepN  = (smalln + 255)/256;
        fused_prep<<<tileN + prepN, 256, 0, stream>>>(matrixs, vectors, w_mat, w1, w2,
                                                      tm, tv, wT, w1T, w2T16, tileN, vecsz);
        render_kernel<true><<<nblk, nthr, 0, stream>>>(rays_o, rays_d, tm, tv,
            nullptr, nullptr, wT, b_mat, w1T, b1, w1, w2T16, b2, out, B, R);
    } else if (ws_size >= need_w){
        f16* wT    = (f16*)d_ws;
        f16* w1T   = wT + 64*96;
        f16* w2T16 = w1T + 64*64;
        const int prepN = (wtot + 255)/256;
        fused_prep<<<prepN, 256, 0, stream>>>(nullptr, nullptr, w_mat, w1, w2,
                                              nullptr, nullptr, wT, w1T, w2T16, 0, 0);
        render_kernel<false><<<nblk, nthr, 0, stream>>>(rays_o, rays_d,
            nullptr, nullptr, matrixs, vectors, wT, b_mat, w1T, b1, w1, w2T16, b2, out, B, R);
    }
}